// Round 1
// baseline (114.317 us; speedup 1.0000x reference)
//
#include <hip/hip_runtime.h>
#include <math.h>

#define T 32
#define K 2048
#define NBLOCKS 256
#define NTHREADS 512
#define HB 128                          // blocks per direction
#define CPB 16                          // columns per block (2 per wave)
#define QS 4                            // K / NTHREADS slots per thread
#define SSTRIDE 32                      // ints: 128 B -> one MALL line per sentinel
#define NSTEP 15                        // R19: balanced 15/15 split (was 16 fwd / 15 bwd)
#define L2E_F 1.4426950408889634f       // log2(e)
#define LN2_F 0.6931471805599453f
#define LOG2PI_F 1.8378770664093453f
#define SP_F     0.17677669529663687f   // sqrt(1/32)
#define LOG_SP_F (-1.7328679513998633f) // ln(sqrt(1/32))
#define CNORM_F  (-(LOG_SP_F) - 0.5f * LOG2PI_F)   // -ln(sp) - 0.5 ln2pi

#if __has_builtin(__builtin_amdgcn_exp2f)
#define EXP2F(x) __builtin_amdgcn_exp2f(x)
#else
#define EXP2F(x) exp2f(x)
#endif
#if __has_builtin(__builtin_amdgcn_logf)
#define LOG2F(x) __builtin_amdgcn_logf(x)
#else
#define LOG2F(x) log2f(x)
#endif

// ALL global sync traffic is relaxed agent-scope atomics (write-through to
// the MALL, bypassing non-coherent per-XCD L2s). NO agent-scope
// release/acquire anywhere (R2/R7: ~15us/step of L2 cache maintenance).
// Producer ordering (data before sentinel) = __syncthreads' per-wave vmcnt
// drain before s_barrier.
__device__ __forceinline__ float aload4(const float* p) {
    return __hip_atomic_load(p, __ATOMIC_RELAXED, __HIP_MEMORY_SCOPE_AGENT);
}
__device__ __forceinline__ void astore4(float* p, float v) {
    __hip_atomic_store(p, v, __ATOMIC_RELAXED, __HIP_MEMORY_SCOPE_AGENT);
}
// R19: packed 8B publish — halves the same-line agent-store count per block
// (16 x 4B from 8 waves -> 8 x 8B), attacking the documented MALL
// same-line serialization. All lanes hold both column results after the
// butterfly reduce, so lane 0 stores the pair.
__device__ __forceinline__ void astore8(float* p, float a, float b) {
    union { float2 f; unsigned long long u; } v;
    v.f = make_float2(a, b);
    __hip_atomic_store((unsigned long long*)p, v.u, __ATOMIC_RELAXED,
                       __HIP_MEMORY_SCOPE_AGENT);
}
__device__ __forceinline__ int sload(const int* p) {
    return __hip_atomic_load(p, __ATOMIC_RELAXED, __HIP_MEMORY_SCOPE_AGENT);
}
__device__ __forceinline__ void sstore(int* p, int v) {
    __hip_atomic_store(p, v, __ATOMIC_RELAXED, __HIP_MEMORY_SCOPE_AGENT);
}

// R15 champion structure (61.7us) + R19 changes:
//  (1) Balanced 15/15 chains + DISTRIBUTED bilinear join: fwd produces r_15,
//      bwd produces c_16; out = lse_{j,k}(r15_j + log2 M15[j,k] + c16_k) - 22.
//      Every block computes the partial for 8 j-rows (j = 8*b + wave) x 2048 k,
//      publishes one scalar into fbuf[b] (row 0 of fbuf is dead after fwd step
//      14) and bumps its OWN spread sentinel to 17. Block 0's wave 0 polls all
//      256 sentinels >= 17 and lse-combines 256 scalars. Removes one full
//      ~3.85us chain step for ~1 extra MALL round trip.
//  (2) MASKED sentinel polling: sentinels are monotone, so satisfied lanes
//      stop re-loading their lines. Cuts steady-state poll traffic ~4-8x.
//  (3) 8B packed column publish (astore8 above).
//  (4) Final reduce is a single-wave shuffle lse (old join burned ~18
//      __syncthreads in an LDS tree).
// Sentinel values: 1..16 chain (step p publishes p+2), 17 = join partial done.
// 0xAAAAAAAA poison is negative -> never satisfies >=, no init kernel needed.
// Ping-pong safety: advancing to step p+2 requires observing all sentinels
// >= p+1, hence every block consumed step p.
__global__ __launch_bounds__(NTHREADS) void fused_kernel(
    const float* __restrict__ means, const float* __restrict__ log_stds,
    const float* __restrict__ eps, float* __restrict__ fbuf,
    float* __restrict__ bbuf, int* __restrict__ fsent, int* __restrict__ bsent,
    float* __restrict__ out)
{
    __shared__ float2 shzD[2][K];    // 32 KB: (z_j, D_j) staging, parity dbuf
    __shared__ float2 lzc[T][CPB];   // own cols: (32*L2E*z, cm2 const)
    __shared__ float smu[T], sstd[T], slq2[T];
    __shared__ float red[NTHREADS];
    __shared__ int ldsflag;

    const int tid  = threadIdx.x;
    const int b    = blockIdx.x;
    const bool fwd = (b < HB);
    const int lb   = fwd ? b : b - HB;
    const int col0 = lb * CPB;

    if (tid == 0) ldsflag = 0;

    // ---- setup: thread (t = tid>>4, dcol = tid&15) handles (t, col0+dcol) ----
    {
        int t = tid >> 4, dcol = tid & 15;
        float mu = means[t];
        float st = expf(log_stds[t]);
        if (dcol == 0) {
            smu[t] = mu; sstd[t] = st;
            slq2[t] = L2E_F * (logf(st) + 0.5f * LOG2PI_F);
        }
        float e = eps[t * K + col0 + dcol];
        float z = fmaf(st, e, mu);
        // (z-mu)/st == e exactly: log_q = -0.5 e^2 - ln(st) - 0.5 ln2pi
        float log_q = fmaf(-0.5f * e, e, -logf(st) - 0.5f * LOG2PI_F);
        float tz2 = (32.0f * L2E_F) * z;
        if (fwd) {
            float cm2 = fmaf((-16.0f * L2E_F) * z, z,
                             L2E_F * (CNORM_F - log_q)) - 11.0f;   // log2K = 11
            lzc[t][dcol] = make_float2(tz2, cm2);
            if (t == 0) {   // seed r_0, parity 0
                float r0 = fmaf(-16.0f * z, z, CNORM_F) - log_q;
                astore4(&fbuf[col0 + dcol], r0 * L2E_F);
            }
        } else {
            float cm2 = fmaf((-16.0f * L2E_F) * z, z, L2E_F * CNORM_F) - 11.0f;
            lzc[t][dcol] = make_float2(tz2, cm2);
            if (t == T - 1) {   // seed c_31 = likelihood, parity 0
                float d = 0.5f - z;
                float c31 = fmaf(-0.5f * d, d, -0.5f * LOG2PI_F);
                astore4(&bbuf[col0 + dcol], c31 * L2E_F);
            }
        }
    }
    __syncthreads();               // drains seed stores (vmcnt) + LDS init
    int* mysent = fwd ? fsent : bsent;
    if (tid == 0) sstore(&mysent[lb * SSTRIDE], 1);

    const int lane = tid & 63;
    const int wave = tid >> 6;     // 0..7: columns 2w, 2w+1
    float* mybuf = fwd ? fbuf : bbuf;

    for (int p = 0; p < NSTEP; ++p) {
        const int par  = p & 1;
        const int need = p + 1;
        const int tin  = fwd ? p : 31 - p;
        const int town = fwd ? p + 1 : 30 - p;
        const float mu_i  = smu[tin];
        const float std_i = sstd[tin];
        const float lqc   = slq2[tin];
        const float* erow = eps + tin * K;

        // ---- pre-poll: z + D-addend for own QS slots (r-independent) ----
        float zloc[QS], dadd[QS];
        #pragma unroll
        for (int q = 0; q < QS; ++q) {
            float e = erow[tid + q * NTHREADS];
            float z = fmaf(std_i, e, mu_i);
            zloc[q] = z;
            float base = fwd ? 0.0f : fmaf((0.5f * L2E_F) * e, e, lqc);
            dadd[q] = fmaf((-16.0f * L2E_F) * z, z, base);
        }

        // ---- detection: wave 0 MASKED-polls own direction's 128 sentinels.
        // Sentinels are monotone, so a satisfied lane never re-loads its
        // line: round 1 issues 128 loads, later rounds only stragglers.
        if (wave == 0) {
            const int* s0 = mysent + lane * SSTRIDE;
            const int* s1 = mysent + (lane + 64) * SSTRIDE;
            bool ok0 = false, ok1 = false;
            for (;;) {
                if (!ok0) ok0 = sload(s0) >= need;
                if (!ok1) ok1 = sload(s1) >= need;
                if (__all(ok0 & ok1)) break;
                __builtin_amdgcn_s_sleep(1);
            }
            __hip_atomic_store(&ldsflag, need, __ATOMIC_RELEASE,
                               __HIP_MEMORY_SCOPE_WORKGROUP);
        } else {
            while (__hip_atomic_load(&ldsflag, __ATOMIC_ACQUIRE,
                                     __HIP_MEMORY_SCOPE_WORKGROUP) < need)
                __builtin_amdgcn_s_sleep(1);
        }

        // ---- one-shot parallel read of the message row + LDS stage ----
        const float* mrow = mybuf + par * K;
        float rv[QS];
        #pragma unroll
        for (int q = 0; q < QS; ++q) rv[q] = aload4(&mrow[tid + q * NTHREADS]);
        #pragma unroll
        for (int q = 0; q < QS; ++q)
            shzD[par][tid + q * NTHREADS] = make_float2(zloc[q], rv[q] + dadd[q]);
        __syncthreads();   // barrier A: stage ready

        // ---- this wave's 2 columns: max pass + exp2 pass over reg'd tiles ----
        const float4* shp = (const float4*)&shzD[par][0];
        float2 zcA = lzc[town][2 * wave];
        float2 zcB = lzc[town][2 * wave + 1];
        float4 fr[16];
        #pragma unroll
        for (int i = 0; i < 16; ++i) fr[i] = shp[lane + (i << 6)];
        float m0 = -INFINITY, m1 = -INFINITY;
        #pragma unroll
        for (int i = 0; i < 16; ++i) {
            m0 = fmaxf(m0, fmaxf(fmaf(zcA.x, fr[i].x, fr[i].y),
                                 fmaf(zcA.x, fr[i].z, fr[i].w)));
            m1 = fmaxf(m1, fmaxf(fmaf(zcB.x, fr[i].x, fr[i].y),
                                 fmaf(zcB.x, fr[i].z, fr[i].w)));
        }
        #pragma unroll
        for (int off = 32; off >= 1; off >>= 1) {
            m0 = fmaxf(m0, __shfl_xor(m0, off, 64));
            m1 = fmaxf(m1, __shfl_xor(m1, off, 64));
        }
        float s0 = 0.0f, s1 = 0.0f;
        #pragma unroll
        for (int i = 0; i < 16; ++i) {
            s0 += EXP2F(fmaf(zcA.x, fr[i].x, fr[i].y) - m0);
            s0 += EXP2F(fmaf(zcA.x, fr[i].z, fr[i].w) - m0);
            s1 += EXP2F(fmaf(zcB.x, fr[i].x, fr[i].y) - m1);
            s1 += EXP2F(fmaf(zcB.x, fr[i].z, fr[i].w) - m1);
        }
        #pragma unroll
        for (int off = 32; off >= 1; off >>= 1) {
            s0 += __shfl_xor(s0, off, 64);
            s1 += __shfl_xor(s1, off, 64);
        }
        if (lane == 0) {
            // one packed 8B store per wave: 8 same-line transactions/block
            astore8(&mybuf[(par ^ 1) * K + col0 + 2 * wave],
                    zcA.y + m0 + LOG2F(s0), zcB.y + m1 + LOG2F(s1));
        }
        // barrier B drains every wave's publish (vmcnt) before s_barrier;
        // only then this block's sentinel advances.
        __syncthreads();
        if (tid == 0) sstore(&mysent[lb * SSTRIDE], p + 2);
    }
    // chains done: fbuf[K+j] = r_15 (log2), bbuf[K+k] = c_16 (log2),
    // own sentinel = 16.

    // ==== R19 distributed bilinear join over M15 (z_15 rows -> z_16 cols) ====
    // wait for BOTH directions' chains (all 256 sentinels >= 16), masked poll
    if (wave == 0) {
        const int* f0 = fsent + lane * SSTRIDE;
        const int* f1 = fsent + (lane + 64) * SSTRIDE;
        const int* g0 = bsent + lane * SSTRIDE;
        const int* g1 = bsent + (lane + 64) * SSTRIDE;
        bool a0 = false, a1 = false, a2 = false, a3 = false;
        for (;;) {
            if (!a0) a0 = sload(f0) >= 16;
            if (!a1) a1 = sload(f1) >= 16;
            if (!a2) a2 = sload(g0) >= 16;
            if (!a3) a3 = sload(g1) >= 16;
            if (__all(a0 & a1 & a2 & a3)) break;
            __builtin_amdgcn_s_sleep(1);
        }
        __hip_atomic_store(&ldsflag, 16, __ATOMIC_RELEASE,
                           __HIP_MEMORY_SCOPE_WORKGROUP);
    } else {
        while (__hip_atomic_load(&ldsflag, __ATOMIC_ACQUIRE,
                                 __HIP_MEMORY_SCOPE_WORKGROUP) < 16)
            __builtin_amdgcn_s_sleep(1);
    }

    // stage (a_k = 32*L2E*z16_k, b_k = c16_k - 16*L2E*z16^2 + L2E*(CNORM - lq16_k))
    // into shzD[0] (dead: step 14's reads ended at its barrier B)
    {
        const float mu16 = smu[16], st16 = sstd[16];
        const float lqc16 = slq2[16] + L2E_F * CNORM_F;
        #pragma unroll
        for (int q = 0; q < QS; ++q) {
            int k = tid + q * NTHREADS;
            float e = eps[16 * K + k];
            float z = fmaf(st16, e, mu16);
            float bk = aload4(&bbuf[K + k]) +
                       fmaf((-16.0f * L2E_F) * z, z,
                            fmaf((0.5f * L2E_F) * e, e, lqc16));
            shzD[0][k] = make_float2((32.0f * L2E_F) * z, bk);
        }
    }
    __syncthreads();

    // each wave owns one j = 8*b + wave: lse over all 2048 k
    {
        const int j = b * 8 + wave;
        float e15 = eps[15 * K + j];
        float zj = fmaf(sstd[15], e15, smu[15]);
        float cj = fmaf((-16.0f * L2E_F) * zj, zj, aload4(&fbuf[K + j]));
        const float4* shp = (const float4*)&shzD[0][0];
        float4 fr[16];
        #pragma unroll
        for (int i = 0; i < 16; ++i) fr[i] = shp[lane + (i << 6)];
        float m = -INFINITY;
        #pragma unroll
        for (int i = 0; i < 16; ++i)
            m = fmaxf(m, fmaxf(fmaf(fr[i].x, zj, fr[i].y),
                               fmaf(fr[i].z, zj, fr[i].w)));
        #pragma unroll
        for (int off = 32; off >= 1; off >>= 1) m = fmaxf(m, __shfl_xor(m, off, 64));
        float s = 0.0f;
        #pragma unroll
        for (int i = 0; i < 16; ++i) {
            s += EXP2F(fmaf(fr[i].x, zj, fr[i].y) - m);
            s += EXP2F(fmaf(fr[i].z, zj, fr[i].w) - m);
        }
        #pragma unroll
        for (int off = 32; off >= 1; off >>= 1) s += __shfl_xor(s, off, 64);
        if (lane == 0) red[wave] = cj + m + LOG2F(s);
    }
    __syncthreads();

    // block partial: lse over this block's 8 j-values -> fbuf[b] (row 0 of
    // fbuf is dead after fwd step 14; every writer observed fsent >= 16
    // before getting here, so all row-0 readers are done)
    if (tid == 0) {
        float m8 = -INFINITY;
        #pragma unroll
        for (int i = 0; i < 8; ++i) m8 = fmaxf(m8, red[i]);
        float s8 = 0.0f;
        #pragma unroll
        for (int i = 0; i < 8; ++i) s8 += EXP2F(red[i] - m8);
        astore4(&fbuf[b], m8 + LOG2F(s8));
    }
    __syncthreads();               // drains the partial store (vmcnt)
    if (tid == 0) sstore(&mysent[lb * SSTRIDE], 17);

    // ---- final: block 0 wave 0 lse-combines 256 partials ----
    if (b == 0 && wave == 0) {
        const int* f0 = fsent + lane * SSTRIDE;
        const int* f1 = fsent + (lane + 64) * SSTRIDE;
        const int* g0 = bsent + lane * SSTRIDE;
        const int* g1 = bsent + (lane + 64) * SSTRIDE;
        bool a0 = false, a1 = false, a2 = false, a3 = false;
        for (;;) {
            if (!a0) a0 = sload(f0) >= 17;
            if (!a1) a1 = sload(f1) >= 17;
            if (!a2) a2 = sload(g0) >= 17;
            if (!a3) a3 = sload(g1) >= 17;
            if (__all(a0 & a1 & a2 & a3)) break;
            __builtin_amdgcn_s_sleep(1);
        }
        float v0 = aload4(&fbuf[lane]);
        float v1 = aload4(&fbuf[lane + 64]);
        float v2 = aload4(&fbuf[lane + 128]);
        float v3 = aload4(&fbuf[lane + 192]);
        float m = fmaxf(fmaxf(v0, v1), fmaxf(v2, v3));
        #pragma unroll
        for (int off = 32; off >= 1; off >>= 1) m = fmaxf(m, __shfl_xor(m, off, 64));
        float s = EXP2F(v0 - m) + EXP2F(v1 - m) + EXP2F(v2 - m) + EXP2F(v3 - m);
        #pragma unroll
        for (int off = 32; off >= 1; off >>= 1) s += __shfl_xor(s, off, 64);
        // -22 = -2*log2 K: M15 matmul-mean's /K + the final /K
        if (lane == 0) out[0] = LN2_F * (m + LOG2F(s) - 22.0f);
    }
}

extern "C" void kernel_launch(void* const* d_in, const int* in_sizes, int n_in,
                              void* d_out, int out_size, void* d_ws, size_t ws_size,
                              hipStream_t stream) {
    const float* means    = (const float*)d_in[0];
    const float* log_stds = (const float*)d_in[1];
    const float* eps      = (const float*)d_in[2];
    float* out = (float*)d_out;

    float* fbuf = (float*)d_ws;                 // 2*K fwd rho ping-pong (16 KB)
    float* bbuf = fbuf + 2 * K;                 // 2*K bwd rho ping-pong (16 KB)
    int*   fsent = (int*)(bbuf + 2 * K);        // 128 fwd sentinels, 128 B apart (16 KB)
    int*   bsent = fsent + 128 * SSTRIDE;       // 128 bwd sentinels, 128 B apart (16 KB)

    fused_kernel<<<NBLOCKS, NTHREADS, 0, stream>>>(
        means, log_stds, eps, fbuf, bbuf, fsent, bsent, out);
}